// Round 8
// baseline (218.722 us; speedup 1.0000x reference)
//
#include <hip/hip_runtime.h>
#include <hip/hip_bf16.h>
#include <stdint.h>

// MHSA fused: B=4, N=2048, D=1024, H=16, Dh=64
// Pipeline: cvt(x) / tcvt(w_qkv) / tcvt(w_out) -> gemm_qkv(256^2) -> flash attn -> gemm_out(256^2)

typedef __attribute__((ext_vector_type(8))) __bf16 bf16x8;
typedef __attribute__((ext_vector_type(4))) __bf16 bf16x4;
typedef __attribute__((ext_vector_type(4))) float f32x4;
typedef __attribute__((ext_vector_type(16))) float f32x16;
typedef __attribute__((ext_vector_type(4))) unsigned int u32x4;

// 0.125 (head-dim scale) * log2(e)
#define EXPC 0.18033688011112042f
// defer-max threshold in raw-score units (0.125*64 = 8 nats -> p <= e^8 fits bf16 easily)
#define THRR 64.0f

static __device__ __forceinline__ void gload_lds16(const void* g, void* s) {
  // dest = wave-uniform LDS base + lane*16B (HW behavior), 16B per lane
  __builtin_amdgcn_global_load_lds(
      (__attribute__((address_space(1))) unsigned int*)g,
      (__attribute__((address_space(3))) unsigned int*)s, 16, 0, 0);
}

// software bf16 pair-pack (validated rounds 3/4/7)
static __device__ __forceinline__ unsigned pk2(float lo, float hi) {
  unsigned short a = __builtin_bit_cast(unsigned short, (__bf16)lo);
  unsigned short b = __builtin_bit_cast(unsigned short, (__bf16)hi);
  return (unsigned)a | ((unsigned)b << 16);
}

// ---------------- f32 -> bf16 flat convert (vectorized) ----------------
__global__ void k_cvt(const float* __restrict__ src, __bf16* __restrict__ dst, int n4) {
  int i = blockIdx.x * blockDim.x + threadIdx.x;
  if (i >= n4) return;
  float4 v = reinterpret_cast<const float4*>(src)[i];
  bf16x4 o = { (__bf16)v.x, (__bf16)v.y, (__bf16)v.z, (__bf16)v.w };
  *reinterpret_cast<bf16x4*>(dst + (size_t)i * 4) = o;
}

// ---------------- transpose + convert: dst[c][r] = src[r][c], src is Hs x W ----
__global__ void k_tcvt(const float* __restrict__ src, __bf16* __restrict__ dst, int W, int Hs) {
  __shared__ float tile[32][33];
  int tx = threadIdx.x, ty = threadIdx.y;  // 32 x 8
  int x = blockIdx.x * 32 + tx;
  int y0 = blockIdx.y * 32;
  for (int j = ty; j < 32; j += 8) tile[j][tx] = src[(size_t)(y0 + j) * W + x];
  __syncthreads();
  int xo = y0 + tx;
  int yo = blockIdx.x * 32;
  for (int j = ty; j < 32; j += 8) dst[(size_t)(yo + j) * Hs + xo] = (__bf16)tile[tx][j];
}

// ---------------- 256^2 GEMM core, triple-buffered counted-vmcnt pipeline ----------
// C(256x256) = A[M][1024] * BT[N][1024]^T. 512 threads = 8 waves (2M x 4N);
// per-wave 128x64 output = acc[8][4] of 16x16 frags. BK=32, 32 K-iters.
// LDS: S[3 bufs][A|B][256 rows][32] bf16 = 96 KB. Stage kt+2 while computing kt;
// s_waitcnt vmcnt(4) + raw s_barrier per iter (kt+1 stays covered by a full
// compute phase; never drains to 0 in the loop). Race-free: buf (kt+2)%3 was
// last read at iter kt-1, whose barrier precedes this stage in program order.
// Chunk XOR swizzle c ^= (row>>1)&3 (8-way bank spread, 2-way residual = free),
// applied via pre-swizzled global source + same XOR on ds_read (both-sides rule).
static __device__ __forceinline__ void gemm256_core(
    const __bf16* __restrict__ A, const __bf16* __restrict__ BT,
    int m0, int n0, f32x4 acc[8][4], __bf16* S) {
  const int tid = threadIdx.x;
  const int lane = tid & 63, wid = tid >> 6;
  const int fr = lane & 15, fq = lane >> 4;
  const int wm = wid >> 2, wn = wid & 3;
  const int rsw = (fr >> 1) & 3;                 // read-side chunk swizzle
  const int srow = tid >> 2;                      // staging row within 128-row issue
  const int scs = (tid & 3) ^ ((tid >> 3) & 3);   // pre-swizzled source chunk
  const int sdst = wid * 512;                     // wave-uniform LDS base (elems)

#pragma unroll
  for (int mi = 0; mi < 8; ++mi)
#pragma unroll
    for (int nj = 0; nj < 4; ++nj) acc[mi][nj] = (f32x4){0.f, 0.f, 0.f, 0.f};

  auto stage = [&](int buf, int kt) {
    __bf16* Sa = S + buf * 16384;
    __bf16* Sb = Sa + 8192;
#pragma unroll
    for (int i = 0; i < 2; ++i) {
      gload_lds16(A  + (size_t)(m0 + i * 128 + srow) * 1024 + kt * 32 + scs * 8,
                  Sa + i * 4096 + sdst);
      gload_lds16(BT + (size_t)(n0 + i * 128 + srow) * 1024 + kt * 32 + scs * 8,
                  Sb + i * 4096 + sdst);
    }
  };

  stage(0, 0);
  stage(1, 1);
  asm volatile("s_waitcnt vmcnt(4)" ::: "memory");   // tile 0 complete, tile 1 in flight
  __builtin_amdgcn_s_barrier();
  __builtin_amdgcn_sched_barrier(0);

  int cur = 0;
  for (int kt = 0; kt < 32; ++kt) {
    if (kt + 2 < 32) {
      int nb = cur + 2; if (nb >= 3) nb -= 3;
      stage(nb, kt + 2);
    }
    const __bf16* Sa = S + cur * 16384;
    const __bf16* Sb = Sa + 8192;
    bf16x8 bfv[4], af[8];
#pragma unroll
    for (int nj = 0; nj < 4; ++nj)
      bfv[nj] = *(const bf16x8*)(Sb + (wn * 64 + nj * 16 + fr) * 32 + ((fq ^ rsw) << 3));
#pragma unroll
    for (int mi = 0; mi < 8; ++mi)
      af[mi] = *(const bf16x8*)(Sa + (wm * 128 + mi * 16 + fr) * 32 + ((fq ^ rsw) << 3));
    __builtin_amdgcn_s_setprio(1);
#pragma unroll
    for (int mi = 0; mi < 8; ++mi)
#pragma unroll
      for (int nj = 0; nj < 4; ++nj)
        acc[mi][nj] = __builtin_amdgcn_mfma_f32_16x16x32_bf16(af[mi], bfv[nj], acc[mi][nj], 0, 0, 0);
    __builtin_amdgcn_s_setprio(0);
    if (kt < 31) {
      if (kt < 30) asm volatile("s_waitcnt vmcnt(4)" ::: "memory");  // kt+1 complete
      else         asm volatile("s_waitcnt vmcnt(0)" ::: "memory");  // tail: last tile
      __builtin_amdgcn_s_barrier();
      __builtin_amdgcn_sched_barrier(0);
    }
    cur = cur + 1 == 3 ? 0 : cur + 1;
  }
}

// C cols 0..3071: [q | k | v]. q,k -> [bh][n][64]; v -> transposed [bh][64][n]
__global__ __launch_bounds__(512, 1) void k_gemm_qkv(
    const __bf16* __restrict__ A, const __bf16* __restrict__ BT,
    __bf16* __restrict__ qb, __bf16* __restrict__ kb, __bf16* __restrict__ vb) {
  __shared__ __align__(16) __bf16 S[3 * 2 * 8192];
  f32x4 acc[8][4];
  int m0 = blockIdx.x * 256, n0 = blockIdx.y * 256;
  gemm256_core(A, BT, m0, n0, acc, S);
  const int lane = threadIdx.x & 63, wid = threadIdx.x >> 6;
  const int fr = lane & 15, fq = lane >> 4;
  const int wm = wid >> 2, wn = wid & 3;
  const int which = n0 >> 10;  // 256-col tile never crosses a q/k/v boundary
#pragma unroll
  for (int mi = 0; mi < 8; ++mi) {
#pragma unroll
    for (int nj = 0; nj < 4; ++nj) {
      int row = m0 + wm * 128 + mi * 16 + fq * 4;    // token index (4 consecutive)
      int col = n0 + wn * 64 + nj * 16 + fr;         // qkv column
      int rem = col & 1023, h = rem >> 6, d = rem & 63;
      int bb = row >> 11, n = row & 2047;            // row..row+3 stay in one b
      int bh = bb * 16 + h;
      if (which == 2) {
        bf16x4 pk = { (__bf16)acc[mi][nj][0], (__bf16)acc[mi][nj][1],
                      (__bf16)acc[mi][nj][2], (__bf16)acc[mi][nj][3] };
        *reinterpret_cast<bf16x4*>(vb + ((size_t)bh * 64 + d) * 2048 + n) = pk;
      } else {
        __bf16* dst = (which == 0) ? qb : kb;
#pragma unroll
        for (int j = 0; j < 4; ++j)
          dst[((size_t)bh * 2048 + (n + j)) * 64 + d] = (__bf16)acc[mi][nj][j];
      }
    }
  }
}

__global__ __launch_bounds__(512, 1) void k_gemm_out(
    const __bf16* __restrict__ A, const __bf16* __restrict__ BT, float* __restrict__ C) {
  __shared__ __align__(16) __bf16 S[3 * 2 * 8192];
  f32x4 acc[8][4];
  int m0 = blockIdx.x * 256, n0 = blockIdx.y * 256;
  gemm256_core(A, BT, m0, n0, acc, S);
  const int lane = threadIdx.x & 63, wid = threadIdx.x >> 6;
  const int fr = lane & 15, fq = lane >> 4;
  const int wm = wid >> 2, wn = wid & 3;
#pragma unroll
  for (int mi = 0; mi < 8; ++mi)
#pragma unroll
    for (int nj = 0; nj < 4; ++nj)
#pragma unroll
      for (int j = 0; j < 4; ++j)
        C[(size_t)(m0 + wm * 128 + mi * 16 + fq * 4 + j) * 1024 + n0 + wn * 64 + nj * 16 + fr] =
            acc[mi][nj][j];
}

// ---------------- flash attention, 4-warp 32x32 swapped structure (round-7) -------
__global__ __launch_bounds__(256, 3) void k_attn(
    const __bf16* __restrict__ qb, const __bf16* __restrict__ kb,
    const __bf16* __restrict__ vb, __bf16* __restrict__ ao) {
  __shared__ __align__(16) __bf16 Ks[2][64 * 64];   // [key][d], swizzled
  __shared__ __align__(16) __bf16 Vs[2][64 * 64];   // [d][key], swizzled (vb pre-transposed)
  const int tid = threadIdx.x, lane = tid & 63, wid = tid >> 6;
  const int r31 = lane & 31, hi = lane >> 5;
  const int lsw = (lane & 7) ^ ((lane >> 3) & 3);   // read-side chunk swizzle
  const int bh = blockIdx.x & 63, qblk = blockIdx.x >> 6;  // same-bh blocks land on one XCD
  const __bf16* kbase = kb + (size_t)bh * 2048 * 64;
  const __bf16* vbase = vb + (size_t)bh * 64 * 2048;

  const int nbase = qblk * 128 + wid * 32;
  const __bf16* qptr = qb + ((size_t)bh * 2048 + nbase + r31) * 64;
  bf16x8 qf[4];
#pragma unroll
  for (int dd = 0; dd < 4; ++dd)
    qf[dd] = *(const bf16x8*)(qptr + dd * 16 + hi * 8);

  f32x16 o0, o1;   // O accum: rows q=crow(r,hi), cols d = dblk*32 + (l&31)
#pragma unroll
  for (int r = 0; r < 16; ++r) { o0[r] = 0.f; o1[r] = 0.f; }
  float m = -1e30f, lsum = 0.f;

  auto stage = [&](int buf, int j0) {
#pragma unroll
    for (int p2 = 0; p2 < 2; ++p2) {
      int row = p2 * 32 + (tid >> 3);
      int sc = (tid & 7) ^ (row & 7) ^ ((row >> 3) & 3);
      int dst = p2 * 2048 + wid * 512;
      gload_lds16(kbase + (size_t)(j0 + row) * 64 + sc * 8, &Ks[buf][dst]);
      gload_lds16(vbase + (size_t)row * 2048 + j0 + sc * 8, &Vs[buf][dst]);
    }
  };

  stage(0, 0);
  __syncthreads();

  for (int kt = 0; kt < 32; ++kt) {
    const int cur = kt & 1;
    if (kt < 31) stage(cur ^ 1, (kt + 1) * 64);

    // ---- S^T = K Q^T ----
    f32x16 sa0, sa1;
#pragma unroll
    for (int r = 0; r < 16; ++r) { sa0[r] = 0.f; sa1[r] = 0.f; }
    __builtin_amdgcn_s_setprio(1);
#pragma unroll
    for (int dd = 0; dd < 4; ++dd) {
      bf16x8 k0 = *(const bf16x8*)(&Ks[cur][r31 * 64 + (((dd * 2 + hi) ^ lsw) << 3)]);
      bf16x8 k1 = *(const bf16x8*)(&Ks[cur][(32 + r31) * 64 + (((dd * 2 + hi) ^ lsw) << 3)]);
      sa0 = __builtin_amdgcn_mfma_f32_32x32x16_bf16(k0, qf[dd], sa0, 0, 0, 0);
      sa1 = __builtin_amdgcn_mfma_f32_32x32x16_bf16(k1, qf[dd], sa1, 0, 0, 0);
    }
    __builtin_amdgcn_s_setprio(0);

    // ---- per-q-row tile max: depth-5 tree + cross-half combine (__shfl_xor) ----
    float mx[8];
#pragma unroll
    for (int r = 0; r < 8; ++r)
      mx[r] = fmaxf(fmaxf(fmaxf(sa0[2 * r], sa0[2 * r + 1]), sa1[2 * r]), sa1[2 * r + 1]);
#pragma unroll
    for (int s = 4; s > 0; s >>= 1)
#pragma unroll
      for (int r = 0; r < s; ++r) mx[r] = fmaxf(mx[r], mx[r + s]);
    float pmax = fmaxf(mx[0], __shfl_xor(mx[0], 32, 64));

    // ---- defer-max ----
    if (!__all(pmax - m <= THRR)) {
      float mn = fmaxf(m, pmax);
      float corr = __builtin_amdgcn_exp2f((m - mn) * EXPC);
      m = mn;
      lsum *= corr;
#pragma unroll
      for (int r = 0; r < 16; ++r) {
        int qrow = (r & 3) + 8 * (r >> 2) + 4 * hi;
        float cr = __shfl(corr, qrow, 64);
        o0[r] *= cr; o1[r] *= cr;
      }
    }

    // ---- P = exp2((s - m)*EXPC): pack pairs immediately (software pk2) ----
    const float mneg = -m * EXPC;
    float rs0 = 0.f, rs1 = 0.f, rs2 = 0.f, rs3 = 0.f;
    unsigned pw0[8], pw1[8];
#pragma unroll
    for (int r = 0; r < 8; ++r) {
      float e0 = __builtin_amdgcn_exp2f(fmaf(sa0[2 * r], EXPC, mneg));
      float e1 = __builtin_amdgcn_exp2f(fmaf(sa0[2 * r + 1], EXPC, mneg));
      float e2 = __builtin_amdgcn_exp2f(fmaf(sa1[2 * r], EXPC, mneg));
      float e3 = __builtin_amdgcn_exp2f(fmaf(sa1[2 * r + 1], EXPC, mneg));
      rs0 += e0; rs1 += e1; rs2 += e2; rs3 += e3;
      pw0[r] = pk2(e0, e1);
      pw1[r] = pk2(e2, e3);
    }
    lsum += (rs0 + rs1) + (rs2 + rs3);

    // ---- build PV A-frags: permlane32_swap redistributes packed halves ----
    unsigned f[4][4];
#pragma unroll
    for (int ks = 0; ks < 2; ++ks) {
      unsigned a0 = pw0[ks * 4 + 0], a1 = pw0[ks * 4 + 1];
      unsigned b0 = pw0[ks * 4 + 2], b1 = pw0[ks * 4 + 3];
      asm("v_permlane32_swap_b32 %0, %1" : "+v"(a0), "+v"(b0));
      asm("v_permlane32_swap_b32 %0, %1" : "+v"(a1), "+v"(b1));
      f[ks][0] = a0; f[ks][1] = a1; f[ks][2] = b0; f[ks][3] = b1;
      unsigned c0 = pw1[ks * 4 + 0], c1 = pw1[ks * 4 + 1];
      unsigned d0 = pw1[ks * 4 + 2], d1 = pw1[ks * 4 + 3];
      asm("v_permlane32_swap_b32 %0, %1" : "+v"(c0), "+v"(d0));
      asm("v_permlane32_swap_b32 %0, %1" : "+v"(c1), "+v"(d1));
      f[2 + ks][0] = c0; f[2 + ks][1] = c1; f[2 + ks][2] = d0; f[2 + ks][3] = d1;
    }

    // ---- O += P V ----
    __builtin_amdgcn_s_setprio(1);
#pragma unroll
    for (int kk = 0; kk < 4; ++kk) {
      u32x4 fw = {f[kk][0], f[kk][1], f[kk][2], f[kk][3]};
      bf16x8 pa = __builtin_bit_cast(bf16x8, fw);
      bf16x8 v0 = *(const bf16x8*)(&Vs[cur][r31 * 64 + (((kk * 2 + hi) ^ lsw) << 3)]);
      bf16x8 v1 = *(const bf16x8*)(&Vs[cur][(32 + r31) * 64 + (((kk * 2 + hi) ^ lsw) << 3)]);
      o0 = __builtin_amdgcn_mfma_f32_32x32x16_bf16(pa, v0, o0, 0, 0, 0);
      o1 = __builtin_amdgcn_mfma_f32_32x32x16_bf16(pa, v1, o1, 0, 0, 0);
    }
    __builtin_amdgcn_s_setprio(0);

    __syncthreads();
  }

  lsum += __shfl_xor(lsum, 32, 64);
  float inv = 1.0f / lsum;
  const int b = bh >> 4, h = bh & 15;
  __bf16* abase = ao + ((size_t)b * 2048 + nbase) * 1024 + h * 64 + r31;
#pragma unroll
  for (int r = 0; r < 16; ++r) {
    int qrow = (r & 3) + 8 * (r >> 2) + 4 * hi;
    float ir = __shfl(inv, qrow, 64);
    abase[(size_t)qrow * 1024] = (__bf16)(o0[r] * ir);
    abase[(size_t)qrow * 1024 + 32] = (__bf16)(o1[r] * ir);
  }
}

extern "C" void kernel_launch(void* const* d_in, const int* in_sizes, int n_in,
                              void* d_out, int out_size, void* d_ws, size_t ws_size,
                              hipStream_t stream) {
  (void)in_sizes; (void)n_in; (void)out_size; (void)ws_size;
  const float* x = (const float*)d_in[0];      // [4,2048,1024]
  const float* w_qkv = (const float*)d_in[1];  // [1024,3072]
  const float* w_out = (const float*)d_in[2];  // [1024,1024]
  float* out = (float*)d_out;                  // [4,2048,1024]

  char* p = (char*)d_ws;
  __bf16* xb    = (__bf16*)p; p += (size_t)8192 * 1024 * 2;  // x bf16 [8192][1024]
  __bf16* wqkvT = (__bf16*)p; p += (size_t)3072 * 1024 * 2;  // w_qkv^T [3072][1024]
  __bf16* woutT = (__bf16*)p; p += (size_t)1024 * 1024 * 2;  // w_out^T [1024][1024]
  __bf16* qb    = (__bf16*)p; p += (size_t)64 * 2048 * 64 * 2;  // [bh][n][d]
  __bf16* kb    = (__bf16*)p; p += (size_t)64 * 2048 * 64 * 2;  // [bh][n][d]
  __bf16* vb    = (__bf16*)p; p += (size_t)64 * 64 * 2048 * 2;  // [bh][d][n]
  __bf16* ao    = (__bf16*)p; p += (size_t)8192 * 1024 * 2;     // [b*n][h*d]

  k_cvt<<<8192, 256, 0, stream>>>(x, xb, 2097152);
  k_tcvt<<<dim3(96, 32), dim3(32, 8), 0, stream>>>(w_qkv, wqkvT, 3072, 1024);
  k_tcvt<<<dim3(32, 32), dim3(32, 8), 0, stream>>>(w_out, woutT, 1024, 1024);
  k_gemm_qkv<<<dim3(32, 12), 512, 0, stream>>>(xb, wqkvT, qb, kb, vb);
  k_attn<<<dim3(1024), dim3(256), 0, stream>>>(qb, kb, vb, ao);
  k_gemm_out<<<dim3(32, 4), 512, 0, stream>>>(ao, woutT, out);
}

// Round 9
// 215.849 us; speedup vs baseline: 1.0133x; 1.0133x over previous
//
#include <hip/hip_runtime.h>
#include <hip/hip_bf16.h>
#include <stdint.h>

// MHSA fused: B=4, N=2048, D=1024, H=16, Dh=64
// Pipeline: cvt(x) / tcvt(w_qkv) / tcvt(w_out) -> gemm_qkv -> flash attn -> gemm_out

typedef __attribute__((ext_vector_type(8))) __bf16 bf16x8;
typedef __attribute__((ext_vector_type(4))) __bf16 bf16x4;
typedef __attribute__((ext_vector_type(4))) float f32x4;
typedef __attribute__((ext_vector_type(16))) float f32x16;
typedef __attribute__((ext_vector_type(4))) unsigned int u32x4;

// 0.125 (head-dim scale) * log2(e)
#define EXPC 0.18033688011112042f
// defer-max threshold in raw-score units (0.125*64 = 8 nats -> p <= e^8 fits bf16 easily)
#define THRR 64.0f

static __device__ __forceinline__ void gload_lds16(const void* g, void* s) {
  // dest = wave-uniform LDS base + lane*16B (HW behavior), 16B per lane
  __builtin_amdgcn_global_load_lds(
      (__attribute__((address_space(1))) unsigned int*)g,
      (__attribute__((address_space(3))) unsigned int*)s, 16, 0, 0);
}

// software bf16 pair-pack (validated rounds 3/4/7)
static __device__ __forceinline__ unsigned pk2(float lo, float hi) {
  unsigned short a = __builtin_bit_cast(unsigned short, (__bf16)lo);
  unsigned short b = __builtin_bit_cast(unsigned short, (__bf16)hi);
  return (unsigned)a | ((unsigned)b << 16);
}

// ---------------- f32 -> bf16 flat convert (vectorized) ----------------
__global__ void k_cvt(const float* __restrict__ src, __bf16* __restrict__ dst, int n4) {
  int i = blockIdx.x * blockDim.x + threadIdx.x;
  if (i >= n4) return;
  float4 v = reinterpret_cast<const float4*>(src)[i];
  bf16x4 o = { (__bf16)v.x, (__bf16)v.y, (__bf16)v.z, (__bf16)v.w };
  *reinterpret_cast<bf16x4*>(dst + (size_t)i * 4) = o;
}

// ---------------- transpose + convert: dst[c][r] = src[r][c], src is Hs x W ----
__global__ void k_tcvt(const float* __restrict__ src, __bf16* __restrict__ dst, int W, int Hs) {
  __shared__ float tile[32][33];
  int tx = threadIdx.x, ty = threadIdx.y;  // 32 x 8
  int x = blockIdx.x * 32 + tx;
  int y0 = blockIdx.y * 32;
  for (int j = ty; j < 32; j += 8) tile[j][tx] = src[(size_t)(y0 + j) * W + x];
  __syncthreads();
  int xo = y0 + tx;
  int yo = blockIdx.x * 32;
  for (int j = ty; j < 32; j += 8) dst[(size_t)(yo + j) * Hs + xo] = (__bf16)tile[tx][j];
}

// ---------------- m97-structure GEMM core: C(128x128) = A[M][K] * BT[N][K]^T ----
// 4 waves, each 64x64 via 4x4 frags of 16x16x32 bf16. BK=32. (round-7 proven)
static __device__ __forceinline__ void gemm_core(
    const __bf16* __restrict__ A, const __bf16* __restrict__ BT, int K,
    int m0, int n0, f32x4 acc[4][4], __bf16* As, __bf16* Bs) {
  const int tid = threadIdx.x;
  const int lane = tid & 63, w = tid >> 6;
  const int fr = lane & 15, fq = lane >> 4;
  const int srow = lane >> 2, scol = (lane & 3) * 8;  // 64 lanes x 16B = 16 rows of 32 bf16
  const int wr = (w >> 1) * 64, wc = (w & 1) * 64;
#pragma unroll
  for (int mi = 0; mi < 4; ++mi)
#pragma unroll
    for (int nj = 0; nj < 4; ++nj) acc[mi][nj] = (f32x4){0.f, 0.f, 0.f, 0.f};

  for (int ko = 0; ko < K; ko += 32) {
#pragma unroll
    for (int i = 0; i < 2; ++i) {
      int rb = w * 32 + i * 16;
      gload_lds16(A + (size_t)(m0 + rb + srow) * K + ko + scol, As + rb * 32);
      gload_lds16(BT + (size_t)(n0 + rb + srow) * K + ko + scol, Bs + rb * 32);
    }
    __syncthreads();
    bf16x8 af[4], bfv[4];
#pragma unroll
    for (int mi = 0; mi < 4; ++mi)
      af[mi] = *(const bf16x8*)(As + (wr + mi * 16 + fr) * 32 + fq * 8);
#pragma unroll
    for (int nj = 0; nj < 4; ++nj)
      bfv[nj] = *(const bf16x8*)(Bs + (wc + nj * 16 + fr) * 32 + fq * 8);
#pragma unroll
    for (int mi = 0; mi < 4; ++mi)
#pragma unroll
      for (int nj = 0; nj < 4; ++nj)
        acc[mi][nj] = __builtin_amdgcn_mfma_f32_16x16x32_bf16(af[mi], bfv[nj], acc[mi][nj], 0, 0, 0);
    __syncthreads();
  }
}

// C cols 0..3071: [q | k | v]. q,k -> [bh][n][64]; v -> transposed [bh][64][n]
__global__ __launch_bounds__(256) void k_gemm_qkv(
    const __bf16* __restrict__ A, const __bf16* __restrict__ BT,
    __bf16* __restrict__ qb, __bf16* __restrict__ kb, __bf16* __restrict__ vb) {
  __shared__ __align__(16) __bf16 As[128 * 32];
  __shared__ __align__(16) __bf16 Bs[128 * 32];
  f32x4 acc[4][4];
  int m0 = blockIdx.x * 128, n0 = blockIdx.y * 128;
  gemm_core(A, BT, 1024, m0, n0, acc, As, Bs);
  const int lane = threadIdx.x & 63, w = threadIdx.x >> 6;
  const int fr = lane & 15, fq = lane >> 4;
  const int wr = (w >> 1) * 64, wc = (w & 1) * 64;
  const int which = n0 >> 10;  // 128-col tile never crosses a q/k/v boundary
#pragma unroll
  for (int mi = 0; mi < 4; ++mi) {
#pragma unroll
    for (int nj = 0; nj < 4; ++nj) {
      int row = m0 + wr + mi * 16 + fq * 4;          // token index (4 consecutive)
      int col = n0 + wc + nj * 16 + fr;              // qkv column
      int rem = col & 1023, h = rem >> 6, d = rem & 63;
      int bb = row >> 11, n = row & 2047;            // row..row+3 stay in one b
      int bh = bb * 16 + h;
      if (which == 2) {
        bf16x4 pk = { (__bf16)acc[mi][nj][0], (__bf16)acc[mi][nj][1],
                      (__bf16)acc[mi][nj][2], (__bf16)acc[mi][nj][3] };
        *reinterpret_cast<bf16x4*>(vb + ((size_t)bh * 64 + d) * 2048 + n) = pk;
      } else {
        __bf16* dst = (which == 0) ? qb : kb;
#pragma unroll
        for (int j = 0; j < 4; ++j)
          dst[((size_t)bh * 2048 + (n + j)) * 64 + d] = (__bf16)acc[mi][nj][j];
      }
    }
  }
}

__global__ __launch_bounds__(256) void k_gemm_out(
    const __bf16* __restrict__ A, const __bf16* __restrict__ BT, float* __restrict__ C) {
  __shared__ __align__(16) __bf16 As[128 * 32];
  __shared__ __align__(16) __bf16 Bs[128 * 32];
  f32x4 acc[4][4];
  int m0 = blockIdx.x * 128, n0 = blockIdx.y * 128;
  gemm_core(A, BT, 1024, m0, n0, acc, As, Bs);
  const int lane = threadIdx.x & 63, w = threadIdx.x >> 6;
  const int fr = lane & 15, fq = lane >> 4;
  const int wr = (w >> 1) * 64, wc = (w & 1) * 64;
#pragma unroll
  for (int mi = 0; mi < 4; ++mi)
#pragma unroll
    for (int nj = 0; nj < 4; ++nj)
#pragma unroll
      for (int j = 0; j < 4; ++j)
        C[(size_t)(m0 + wr + mi * 16 + fq * 4 + j) * 1024 + n0 + wc + nj * 16 + fr] =
            acc[mi][nj][j];
}

// ---------------- flash attention, 4-warp 32x32 swapped structure ----------------
// Round-7 math, register-dieted: Q lives in LDS (staged once, same XOR swizzle as K;
// conflict-free by the identical row-based derivation), PV A-frags built per-kk from
// pw words (each consumed once; swaps between distinct-valued regs — validated pattern).
// Target: unified regs <= 170 -> 3 blocks/CU (LDS 48KB x 3 = 144 <= 160).
__global__ __launch_bounds__(256, 3) void k_attn(
    const __bf16* __restrict__ qb, const __bf16* __restrict__ kb,
    const __bf16* __restrict__ vb, __bf16* __restrict__ ao) {
  __shared__ __align__(16) __bf16 Ks[2][64 * 64];   // [key][d], swizzled
  __shared__ __align__(16) __bf16 Vs[2][64 * 64];   // [d][key], swizzled (vb pre-transposed)
  __shared__ __align__(16) __bf16 Qs[4][32 * 64];   // per-warp [q][d], swizzled
  const int tid = threadIdx.x, lane = tid & 63, wid = tid >> 6;
  const int r31 = lane & 31, hi = lane >> 5;
  const int lsw = (lane & 7) ^ ((lane >> 3) & 3);   // read-side chunk swizzle (row = r31)
  const int bh = blockIdx.x & 63, qblk = blockIdx.x >> 6;  // same-bh blocks land on one XCD
  const __bf16* kbase = kb + (size_t)bh * 2048 * 64;
  const __bf16* vbase = vb + (size_t)bh * 64 * 2048;

  const int nbase = qblk * 128 + wid * 32;

  f32x16 o0, o1;   // O accum: rows q=crow(r,hi), cols d = dblk*32 + (l&31)
#pragma unroll
  for (int r = 0; r < 16; ++r) { o0[r] = 0.f; o1[r] = 0.f; }
  float m = -1e30f, lsum = 0.f;  // per q-row (q = l&31); lsum = own-half partial

  // staging: 256 threads x 2 passes; pass p covers rows p*32..p*32+31 (8 rows/wave/pass)
  auto stage = [&](int buf, int j0) {
#pragma unroll
    for (int p2 = 0; p2 < 2; ++p2) {
      int row = p2 * 32 + (tid >> 3);
      int sc = (tid & 7) ^ (row & 7) ^ ((row >> 3) & 3);  // pre-swizzled source chunk
      int dst = p2 * 2048 + wid * 512;                    // wave-uniform LDS base (elems)
      gload_lds16(kbase + (size_t)(j0 + row) * 64 + sc * 8, &Ks[buf][dst]);
      gload_lds16(vbase + (size_t)row * 2048 + j0 + sc * 8, &Vs[buf][dst]);
    }
  };

  // Q staging (once): per warp 32 rows x 8 chunks = 4 issues of 64 lanes
#pragma unroll
  for (int i = 0; i < 4; ++i) {
    int qr = i * 8 + (lane >> 3);
    int qc = (lane & 7) ^ (qr & 7) ^ ((qr >> 3) & 3);
    gload_lds16(qb + ((size_t)bh * 2048 + nbase + qr) * 64 + qc * 8, &Qs[wid][i * 512]);
  }
  stage(0, 0);
  __syncthreads();

  for (int kt = 0; kt < 32; ++kt) {
    const int cur = kt & 1;
    if (kt < 31) stage(cur ^ 1, (kt + 1) * 64);   // prefetch next tile under compute

    // ---- S^T = K Q^T: A = K-frag (rows=keys), B = Q-frag (cols=q, from LDS) ----
    f32x16 sa0, sa1;
#pragma unroll
    for (int r = 0; r < 16; ++r) { sa0[r] = 0.f; sa1[r] = 0.f; }
    __builtin_amdgcn_s_setprio(1);
#pragma unroll
    for (int dd = 0; dd < 4; ++dd) {
      bf16x8 qv = *(const bf16x8*)(&Qs[wid][r31 * 64 + (((dd * 2 + hi) ^ lsw) << 3)]);
      bf16x8 k0 = *(const bf16x8*)(&Ks[cur][r31 * 64 + (((dd * 2 + hi) ^ lsw) << 3)]);
      bf16x8 k1 = *(const bf16x8*)(&Ks[cur][(32 + r31) * 64 + (((dd * 2 + hi) ^ lsw) << 3)]);
      sa0 = __builtin_amdgcn_mfma_f32_32x32x16_bf16(k0, qv, sa0, 0, 0, 0);
      sa1 = __builtin_amdgcn_mfma_f32_32x32x16_bf16(k1, qv, sa1, 0, 0, 0);
    }
    __builtin_amdgcn_s_setprio(0);

    // ---- per-q-row tile max: depth-5 tree + cross-half combine (__shfl_xor) ----
    float mx[8];
#pragma unroll
    for (int r = 0; r < 8; ++r)
      mx[r] = fmaxf(fmaxf(fmaxf(sa0[2 * r], sa0[2 * r + 1]), sa1[2 * r]), sa1[2 * r + 1]);
#pragma unroll
    for (int s = 4; s > 0; s >>= 1)
#pragma unroll
      for (int r = 0; r < s; ++r) mx[r] = fmaxf(mx[r], mx[r + s]);
    float pmax = fmaxf(mx[0], __shfl_xor(mx[0], 32, 64));

    // ---- defer-max: rescale only when some row's max grew past THR ----
    if (!__all(pmax - m <= THRR)) {
      float mn = fmaxf(m, pmax);
      float corr = __builtin_amdgcn_exp2f((m - mn) * EXPC);
      m = mn;
      lsum *= corr;
#pragma unroll
      for (int r = 0; r < 16; ++r) {
        int qrow = (r & 3) + 8 * (r >> 2) + 4 * hi;
        float cr = __shfl(corr, qrow, 64);   // corr lives at lane q (=q-row index)
        o0[r] *= cr; o1[r] *= cr;
      }
    }

    // ---- P = exp2((s - m)*EXPC): pack pairs immediately (software pk2) ----
    const float mneg = -m * EXPC;
    float rs0 = 0.f, rs1 = 0.f, rs2 = 0.f, rs3 = 0.f;
    unsigned pw0[8], pw1[8];
#pragma unroll
    for (int r = 0; r < 8; ++r) {
      float e0 = __builtin_amdgcn_exp2f(fmaf(sa0[2 * r], EXPC, mneg));
      float e1 = __builtin_amdgcn_exp2f(fmaf(sa0[2 * r + 1], EXPC, mneg));
      float e2 = __builtin_amdgcn_exp2f(fmaf(sa1[2 * r], EXPC, mneg));
      float e3 = __builtin_amdgcn_exp2f(fmaf(sa1[2 * r + 1], EXPC, mneg));
      rs0 += e0; rs1 += e1; rs2 += e2; rs3 += e3;
      pw0[r] = pk2(e0, e1);
      pw1[r] = pk2(e2, e3);
    }
    lsum += (rs0 + rs1) + (rs2 + rs3);

    // ---- O += P V: per-kk frag build (permlane32_swap) + MFMA, words consumed once ----
    __builtin_amdgcn_s_setprio(1);
#define PVSTEP(W0, W1, W2, W3, KK) do {                                              \
      unsigned a0 = (W0), a1 = (W1), b0 = (W2), b1 = (W3);                           \
      asm("v_permlane32_swap_b32 %0, %1" : "+v"(a0), "+v"(b0));                      \
      asm("v_permlane32_swap_b32 %0, %1" : "+v"(a1), "+v"(b1));                      \
      u32x4 fw = {a0, a1, b0, b1};                                                   \
      bf16x8 pa = __builtin_bit_cast(bf16x8, fw);                                    \
      bf16x8 v0 = *(const bf16x8*)(&Vs[cur][r31 * 64 + ((((KK)*2 + hi) ^ lsw) << 3)]); \
      bf16x8 v1 = *(const bf16x8*)(&Vs[cur][(32 + r31) * 64 + ((((KK)*2 + hi) ^ lsw) << 3)]); \
      o0 = __builtin_amdgcn_mfma_f32_32x32x16_bf16(pa, v0, o0, 0, 0, 0);             \
      o1 = __builtin_amdgcn_mfma_f32_32x32x16_bf16(pa, v1, o1, 0, 0, 0);             \
    } while (0)
    PVSTEP(pw0[0], pw0[1], pw0[2], pw0[3], 0);
    PVSTEP(pw0[4], pw0[5], pw0[6], pw0[7], 1);
    PVSTEP(pw1[0], pw1[1], pw1[2], pw1[3], 2);
    PVSTEP(pw1[4], pw1[5], pw1[6], pw1[7], 3);
#undef PVSTEP
    __builtin_amdgcn_s_setprio(0);

    __syncthreads();  // prefetch drained (hidden under compute) + buffer swap
  }

  // ---- epilogue: combine halves (__shfl_xor), normalize, store ----
  lsum += __shfl_xor(lsum, 32, 64);
  float inv = 1.0f / lsum;
  const int b = bh >> 4, h = bh & 15;
  __bf16* abase = ao + ((size_t)b * 2048 + nbase) * 1024 + h * 64 + r31;
#pragma unroll
  for (int r = 0; r < 16; ++r) {
    int qrow = (r & 3) + 8 * (r >> 2) + 4 * hi;
    float ir = __shfl(inv, qrow, 64);
    abase[(size_t)qrow * 1024] = (__bf16)(o0[r] * ir);
    abase[(size_t)qrow * 1024 + 32] = (__bf16)(o1[r] * ir);
  }
}

extern "C" void kernel_launch(void* const* d_in, const int* in_sizes, int n_in,
                              void* d_out, int out_size, void* d_ws, size_t ws_size,
                              hipStream_t stream) {
  (void)in_sizes; (void)n_in; (void)out_size; (void)ws_size;
  const float* x = (const float*)d_in[0];      // [4,2048,1024]
  const float* w_qkv = (const float*)d_in[1];  // [1024,3072]
  const float* w_out = (const float*)d_in[2];  // [1024,1024]
  float* out = (float*)d_out;                  // [4,2048,1024]

  char* p = (char*)d_ws;
  __bf16* xb    = (__bf16*)p; p += (size_t)8192 * 1024 * 2;  // x bf16 [8192][1024]
  __bf16* wqkvT = (__bf16*)p; p += (size_t)3072 * 1024 * 2;  // w_qkv^T [3072][1024]
  __bf16* woutT = (__bf16*)p; p += (size_t)1024 * 1024 * 2;  // w_out^T [1024][1024]
  __bf16* qb    = (__bf16*)p; p += (size_t)64 * 2048 * 64 * 2;  // [bh][n][d]
  __bf16* kb    = (__bf16*)p; p += (size_t)64 * 2048 * 64 * 2;  // [bh][n][d]
  __bf16* vb    = (__bf16*)p; p += (size_t)64 * 64 * 2048 * 2;  // [bh][d][n]
  __bf16* ao    = (__bf16*)p; p += (size_t)8192 * 1024 * 2;     // [b*n][h*d]

  k_cvt<<<8192, 256, 0, stream>>>(x, xb, 2097152);
  k_tcvt<<<dim3(96, 32), dim3(32, 8), 0, stream>>>(w_qkv, wqkvT, 3072, 1024);
  k_tcvt<<<dim3(32, 32), dim3(32, 8), 0, stream>>>(w_out, woutT, 1024, 1024);
  k_gemm_qkv<<<dim3(64, 24), 256, 0, stream>>>(xb, wqkvT, qb, kb, vb);
  k_attn<<<dim3(1024), dim3(256), 0, stream>>>(qb, kb, vb, ao);
  k_gemm_out<<<dim3(64, 8), 256, 0, stream>>>(ao, woutT, out);
}